// Round 12
// baseline (182.450 us; speedup 1.0000x reference)
//
#include <hip/hip_runtime.h>
#include <hip/hip_bf16.h>

#define N_NODES 50000
#define N_EDGES 625000
#define D 128
#define CAP 64                         // max in-degree slots (mean 12.5; P(>=64) ~ 1e-30)
#define NTILES ((N_NODES + 15) / 16)   // 3125
#define NRANGE 8
#define RSPAN (N_NODES / NRANGE)       // 6250
#define FILL_BLOCKS 1024               // role-A blocks
#define XW_BLOCKS 1024                 // role-B blocks
#define CHUNK 2048                     // edges per work-queue claim
#define NCHUNK ((N_EDGES + CHUNK - 1) / CHUNK)  // 306

typedef __attribute__((ext_vector_type(8))) short bf16x8;
typedef __attribute__((ext_vector_type(4))) float f32x4;

__device__ __forceinline__ float b2f(short s) {
    unsigned u = ((unsigned)(unsigned short)s) << 16;
    return __uint_as_float(u);
}
__device__ __forceinline__ short f2b(float f) {
    union { __hip_bfloat16 h; short s; } cv;
    cv.h = __float2bfloat16(f);
    return cv.s;
}

// ---- zero deg + work-queue cursors (ws poisoned 0xAA once per session) ----
__global__ void k_zero(int* __restrict__ deg, int* __restrict__ cursor) {
    int i = blockIdx.x * 256 + threadIdx.x;
    if (i < N_NODES) deg[i] = 0;
    if (i < NRANGE) cursor[i] = 0;
}

// ---- merged prep.
//  Blocks [0,1024): padded-CSR fill partitioned by TRUE XCD id (s_getreg
//  HW_REG_XCC_ID): each block drains its own XCD's dst-range chunk queue,
//  then work-steals other ranges (correct under any dispatch mapping).
//  colp/deg lines of range g are dirtied only from XCD g -> written back once.
//  Blocks [1024,2048): y = bf16(x @ W^T) unscaled (no dependency on fill). ----
__global__ __launch_bounds__(256) void k_prep(const int* __restrict__ src,
                                              const int* __restrict__ dst,
                                              int* __restrict__ deg,
                                              unsigned short* __restrict__ colp,
                                              int* __restrict__ cursor,
                                              const float* __restrict__ x,
                                              const float* __restrict__ w,
                                              short* __restrict__ y) {
    int b = blockIdx.x;
    if (b < FILL_BLOCKS) {
        unsigned xcc;
        asm volatile("s_getreg_b32 %0, hwreg(HW_REG_XCC_ID)" : "=s"(xcc));
        int myg = (int)(xcc & 7u);
        __shared__ int s_c;
        for (int gi = 0; gi < NRANGE; ++gi) {
            int g = (myg + gi) & 7;
            int lo = g * RSPAN, hi = lo + RSPAN;
            for (;;) {
                if (threadIdx.x == 0) s_c = atomicAdd(&cursor[g], 1);
                __syncthreads();
                int c = s_c;
                __syncthreads();
                if (c >= NCHUNK) break;
                int e0 = c * CHUNK + threadIdx.x;
                #pragma unroll
                for (int k = 0; k < CHUNK / 256; ++k) {
                    int e = e0 + k * 256;
                    if (e < N_EDGES) {
                        int d = dst[e];
                        if (d >= lo && d < hi) {
                            int p = atomicAdd(&deg[d], 1);
                            if (p < CAP) colp[d * CAP + p] = (unsigned short)src[e];
                        }
                    }
                }
            }
        }
    } else {
        // ---- xw role ----
        int t = threadIdx.x;
        int wave = t >> 6, lane = t & 63;
        int c0 = wave * 32;
        int lr = lane & 15;
        int lk = (lane >> 4) * 8;

        // persistent W fragments (f32 -> bf16 once): 4 k-steps x 2 col-tiles
        bf16x8 wf0[4], wf1[4];
        {
            const float* wp0 = w + (size_t)(c0 + lr) * D + lk;
            const float* wp1 = wp0 + 16 * D;
            #pragma unroll
            for (int ks = 0; ks < 4; ++ks) {
                f32x4 wa0 = *(const f32x4*)(wp0 + ks * 32);
                f32x4 wb0 = *(const f32x4*)(wp0 + ks * 32 + 4);
                f32x4 wa1 = *(const f32x4*)(wp1 + ks * 32);
                f32x4 wb1 = *(const f32x4*)(wp1 + ks * 32 + 4);
                #pragma unroll
                for (int q = 0; q < 4; ++q) {
                    wf0[ks][q] = f2b(wa0[q]); wf0[ks][q + 4] = f2b(wb0[q]);
                    wf1[ks][q] = f2b(wa1[q]); wf1[ks][q + 4] = f2b(wb1[q]);
                }
            }
        }

        for (int tile = b - FILL_BLOCKS; tile < NTILES; tile += XW_BLOCKS) {
            int row0 = tile * 16;
            const float* ap = x + (size_t)(row0 + lr) * D + lk;
            f32x4 acc0 = {0.f, 0.f, 0.f, 0.f};
            f32x4 acc1 = {0.f, 0.f, 0.f, 0.f};
            #pragma unroll
            for (int ks = 0; ks < 4; ++ks) {
                f32x4 xa = *(const f32x4*)(ap + ks * 32);
                f32x4 xb = *(const f32x4*)(ap + ks * 32 + 4);
                bf16x8 a;
                #pragma unroll
                for (int q = 0; q < 4; ++q) { a[q] = f2b(xa[q]); a[q + 4] = f2b(xb[q]); }
                acc0 = __builtin_amdgcn_mfma_f32_16x16x32_bf16(a, wf0[ks], acc0, 0, 0, 0);
                acc1 = __builtin_amdgcn_mfma_f32_16x16x32_bf16(a, wf1[ks], acc1, 0, 0, 0);
            }
            // D layout: col = lane&15, row = (lane>>4)*4 + i (m89-verified)
            int orow = row0 + (lane >> 4) * 4;
            int oc0 = c0 + lr, oc1 = c0 + 16 + lr;
            #pragma unroll
            for (int i = 0; i < 4; ++i) {
                y[(size_t)(orow + i) * D + oc0] = f2b(acc0[i]);
                y[(size_t)(orow + i) * D + oc1] = f2b(acc1[i]);
            }
        }
    }
}

// ---- gather: out[n] = dd*( sum_s ds*y[s] + dd*y[n] ) + bias, d* = rsqrt(deg+1).
//      16 lanes/node; per 16 neighbors: one coalesced ushort index batch +
//      one scattered deg load -> rsqrt; (idx, scale) shfl-broadcast. ----
__global__ __launch_bounds__(256) void k_gather(const short* __restrict__ y,
                                                const int* __restrict__ deg,
                                                const unsigned short* __restrict__ colp,
                                                const float* __restrict__ bias,
                                                float* __restrict__ out) {
    int tid = blockIdx.x * 256 + threadIdx.x;
    int n = tid >> 4;            // node id (16 lanes per node)
    int sub = threadIdx.x & 15;  // 8-channel chunk
    int lane = threadIdx.x & 63;
    int gb = lane & 48;          // 16-lane group base within the wave
    if (n >= N_NODES) return;
    int dn_raw = deg[n];
    float dd = rsqrtf((float)(dn_raw + 1));
    int dn = dn_raw < CAP ? dn_raw : CAP;
    bf16x8 self = *(const bf16x8*)(y + (size_t)n * D + sub * 8);
    float acc0[8], acc1[8];
    #pragma unroll
    for (int q = 0; q < 8; ++q) { acc0[q] = dd * b2f(self[q]); acc1[q] = 0.f; }
    const unsigned short* cp = colp + (size_t)n * CAP;

    for (int bj = 0; bj < dn; bj += 16) {
        int rem = dn - bj;
        int m = rem < 16 ? rem : 16;
        int cidx = 0;
        float cds = 0.f;
        if (sub < m) {
            cidx = cp[bj + sub];                   // one coalesced 32B batch
            cds = rsqrtf((float)(deg[cidx] + 1));  // one scattered 4B/lane
        }
        int j = 0;
        for (; j + 4 <= m; j += 4) {
            int s0 = __shfl(cidx, gb + j + 0);
            int s1 = __shfl(cidx, gb + j + 1);
            int s2 = __shfl(cidx, gb + j + 2);
            int s3 = __shfl(cidx, gb + j + 3);
            float d0 = __shfl(cds, gb + j + 0);
            float d1 = __shfl(cds, gb + j + 1);
            float d2 = __shfl(cds, gb + j + 2);
            float d3 = __shfl(cds, gb + j + 3);
            bf16x8 v0 = *(const bf16x8*)(y + (size_t)s0 * D + sub * 8);
            bf16x8 v1 = *(const bf16x8*)(y + (size_t)s1 * D + sub * 8);
            bf16x8 v2 = *(const bf16x8*)(y + (size_t)s2 * D + sub * 8);
            bf16x8 v3 = *(const bf16x8*)(y + (size_t)s3 * D + sub * 8);
            #pragma unroll
            for (int q = 0; q < 8; ++q) {
                acc0[q] += d0 * b2f(v0[q]) + d2 * b2f(v2[q]);
                acc1[q] += d1 * b2f(v1[q]) + d3 * b2f(v3[q]);
            }
        }
        for (; j < m; ++j) {
            int s0 = __shfl(cidx, gb + j);
            float d0 = __shfl(cds, gb + j);
            bf16x8 v0 = *(const bf16x8*)(y + (size_t)s0 * D + sub * 8);
            #pragma unroll
            for (int q = 0; q < 8; ++q) acc0[q] += d0 * b2f(v0[q]);
        }
    }

    const float4* bch = (const float4*)(bias + sub * 8);
    float4 bb0 = bch[0], bb1 = bch[1];
    float4 o0, o1;
    o0.x = dd * (acc0[0] + acc1[0]) + bb0.x; o0.y = dd * (acc0[1] + acc1[1]) + bb0.y;
    o0.z = dd * (acc0[2] + acc1[2]) + bb0.z; o0.w = dd * (acc0[3] + acc1[3]) + bb0.w;
    o1.x = dd * (acc0[4] + acc1[4]) + bb1.x; o1.y = dd * (acc0[5] + acc1[5]) + bb1.y;
    o1.z = dd * (acc0[6] + acc1[6]) + bb1.z; o1.w = dd * (acc0[7] + acc1[7]) + bb1.w;
    float4* op = (float4*)(out + (size_t)n * D + sub * 8);
    op[0] = o0; op[1] = o1;
}

extern "C" void kernel_launch(void* const* d_in, const int* in_sizes, int n_in,
                              void* d_out, int out_size, void* d_ws, size_t ws_size,
                              hipStream_t stream) {
    const float* x    = (const float*)d_in[0];
    const int*   ei   = (const int*)d_in[1];   // [2, E]: row0=src, row1=dst
    const float* w    = (const float*)d_in[2];
    const float* bias = (const float*)d_in[3];
    float* out = (float*)d_out;

    const int* src = ei;
    const int* dst = ei + N_EDGES;

    // workspace carve
    char* p = (char*)d_ws;
    short* y  = (short*)p;             p += (size_t)N_NODES * D * 2;    // 12.8 MB
    int* deg  = (int*)p;               p += (size_t)N_NODES * 4;        // 200 KB
    unsigned short* colp = (unsigned short*)p;
    p += (size_t)N_NODES * CAP * 2;                                     // 6.4 MB
    int* cursor = (int*)p;             p += 64 * 4;

    k_zero<<<(N_NODES + 255) / 256, 256, 0, stream>>>(deg, cursor);
    k_prep<<<FILL_BLOCKS + XW_BLOCKS, 256, 0, stream>>>(src, dst, deg, colp, cursor, x, w, y);
    k_gather<<<((N_NODES * 16) + 255) / 256, 256, 0, stream>>>(y, deg, colp, bias, out);
}

// Round 13
// 89.351 us; speedup vs baseline: 2.0420x; 2.0420x over previous
//
#include <hip/hip_runtime.h>
#include <hip/hip_bf16.h>

#define N_NODES 50000
#define N_EDGES 625000
#define D 128
#define CAP 64                         // max in-degree slots (mean 12.5, max ~30; P(>=64) ~ 1e-30)
#define NTILES ((N_NODES + 15) / 16)   // 3125
#define PREP_BLOCKS 2048

typedef __attribute__((ext_vector_type(8))) short bf16x8;
typedef __attribute__((ext_vector_type(4))) float f32x4;

__device__ __forceinline__ float b2f(short s) {
    unsigned u = ((unsigned)(unsigned short)s) << 16;
    return __uint_as_float(u);
}
__device__ __forceinline__ short f2b(float f) {
    union { __hip_bfloat16 h; short s; } cv;
    cv.h = __float2bfloat16(f);
    return cv.s;
}

// ---- zero deg (ws poisoned 0xAA once; deg must be zeroed every call) ----
__global__ void k_zero(int* __restrict__ deg) {
    int i = blockIdx.x * 256 + threadIdx.x;
    if (i < N_NODES) deg[i] = 0;
}

// ---- merged prep, role-fluid: ALL blocks do one single-pass CSR fill
//      (no range filter: 1x edge read, 16x less fill work per block than R11),
//      then fall through to the xw GEMM on a static 2-tile schedule. ----
__global__ __launch_bounds__(256) void k_prep(const int* __restrict__ src,
                                              const int* __restrict__ dst,
                                              int* __restrict__ deg,
                                              unsigned short* __restrict__ colp,
                                              const float* __restrict__ x,
                                              const float* __restrict__ w,
                                              short* __restrict__ y) {
    int b = blockIdx.x;
    int t = threadIdx.x;

    // ---- phase 1: padded-CSR fill, one pass, all blocks ----
    for (int e = b * 256 + t; e < N_EDGES; e += PREP_BLOCKS * 256) {
        int d = dst[e];
        int p = atomicAdd(&deg[d], 1);
        if (p < CAP) colp[d * CAP + p] = (unsigned short)src[e];
    }

    // ---- phase 2: y = bf16(x @ W^T) unscaled; static tile schedule ----
    int wave = t >> 6, lane = t & 63;
    int c0 = wave * 32;
    int lr = lane & 15;
    int lk = (lane >> 4) * 8;

    // persistent W fragments (f32 -> bf16 once): 4 k-steps x 2 col-tiles
    bf16x8 wf0[4], wf1[4];
    {
        const float* wp0 = w + (size_t)(c0 + lr) * D + lk;
        const float* wp1 = wp0 + 16 * D;
        #pragma unroll
        for (int ks = 0; ks < 4; ++ks) {
            f32x4 wa0 = *(const f32x4*)(wp0 + ks * 32);
            f32x4 wb0 = *(const f32x4*)(wp0 + ks * 32 + 4);
            f32x4 wa1 = *(const f32x4*)(wp1 + ks * 32);
            f32x4 wb1 = *(const f32x4*)(wp1 + ks * 32 + 4);
            #pragma unroll
            for (int q = 0; q < 4; ++q) {
                wf0[ks][q] = f2b(wa0[q]); wf0[ks][q + 4] = f2b(wb0[q]);
                wf1[ks][q] = f2b(wa1[q]); wf1[ks][q + 4] = f2b(wb1[q]);
            }
        }
    }

    for (int tile = b; tile < NTILES; tile += PREP_BLOCKS) {
        int row0 = tile * 16;
        const float* ap = x + (size_t)(row0 + lr) * D + lk;
        f32x4 acc0 = {0.f, 0.f, 0.f, 0.f};
        f32x4 acc1 = {0.f, 0.f, 0.f, 0.f};
        #pragma unroll
        for (int ks = 0; ks < 4; ++ks) {
            f32x4 xa = *(const f32x4*)(ap + ks * 32);
            f32x4 xb = *(const f32x4*)(ap + ks * 32 + 4);
            bf16x8 a;
            #pragma unroll
            for (int q = 0; q < 4; ++q) { a[q] = f2b(xa[q]); a[q + 4] = f2b(xb[q]); }
            acc0 = __builtin_amdgcn_mfma_f32_16x16x32_bf16(a, wf0[ks], acc0, 0, 0, 0);
            acc1 = __builtin_amdgcn_mfma_f32_16x16x32_bf16(a, wf1[ks], acc1, 0, 0, 0);
        }
        // D layout: col = lane&15, row = (lane>>4)*4 + i (m89-verified)
        int orow = row0 + (lane >> 4) * 4;
        int oc0 = c0 + lr, oc1 = c0 + 16 + lr;
        #pragma unroll
        for (int i = 0; i < 4; ++i) {
            y[(size_t)(orow + i) * D + oc0] = f2b(acc0[i]);
            y[(size_t)(orow + i) * D + oc1] = f2b(acc1[i]);
        }
    }
}

// ---- gather: out[n] = dd*( sum_s ds*y[s] + dd*y[n] ) + bias, d* = rsqrt(deg+1).
//      16 lanes/node; per 16 neighbors: one coalesced ushort index batch +
//      one scattered deg load -> rsqrt; (idx, scale) shfl-broadcast. ----
__global__ __launch_bounds__(256) void k_gather(const short* __restrict__ y,
                                                const int* __restrict__ deg,
                                                const unsigned short* __restrict__ colp,
                                                const float* __restrict__ bias,
                                                float* __restrict__ out) {
    int tid = blockIdx.x * 256 + threadIdx.x;
    int n = tid >> 4;            // node id (16 lanes per node)
    int sub = threadIdx.x & 15;  // 8-channel chunk
    int lane = threadIdx.x & 63;
    int gb = lane & 48;          // 16-lane group base within the wave
    if (n >= N_NODES) return;
    int dn_raw = deg[n];
    float dd = rsqrtf((float)(dn_raw + 1));
    int dn = dn_raw < CAP ? dn_raw : CAP;
    bf16x8 self = *(const bf16x8*)(y + (size_t)n * D + sub * 8);
    float acc0[8], acc1[8];
    #pragma unroll
    for (int q = 0; q < 8; ++q) { acc0[q] = dd * b2f(self[q]); acc1[q] = 0.f; }
    const unsigned short* cp = colp + (size_t)n * CAP;

    for (int bj = 0; bj < dn; bj += 16) {
        int rem = dn - bj;
        int m = rem < 16 ? rem : 16;
        int cidx = 0;
        float cds = 0.f;
        if (sub < m) {
            cidx = cp[bj + sub];                   // one coalesced 32B batch
            cds = rsqrtf((float)(deg[cidx] + 1));  // one scattered 4B/lane
        }
        int j = 0;
        for (; j + 4 <= m; j += 4) {
            int s0 = __shfl(cidx, gb + j + 0);
            int s1 = __shfl(cidx, gb + j + 1);
            int s2 = __shfl(cidx, gb + j + 2);
            int s3 = __shfl(cidx, gb + j + 3);
            float d0 = __shfl(cds, gb + j + 0);
            float d1 = __shfl(cds, gb + j + 1);
            float d2 = __shfl(cds, gb + j + 2);
            float d3 = __shfl(cds, gb + j + 3);
            bf16x8 v0 = *(const bf16x8*)(y + (size_t)s0 * D + sub * 8);
            bf16x8 v1 = *(const bf16x8*)(y + (size_t)s1 * D + sub * 8);
            bf16x8 v2 = *(const bf16x8*)(y + (size_t)s2 * D + sub * 8);
            bf16x8 v3 = *(const bf16x8*)(y + (size_t)s3 * D + sub * 8);
            #pragma unroll
            for (int q = 0; q < 8; ++q) {
                acc0[q] += d0 * b2f(v0[q]) + d2 * b2f(v2[q]);
                acc1[q] += d1 * b2f(v1[q]) + d3 * b2f(v3[q]);
            }
        }
        for (; j < m; ++j) {
            int s0 = __shfl(cidx, gb + j);
            float d0 = __shfl(cds, gb + j);
            bf16x8 v0 = *(const bf16x8*)(y + (size_t)s0 * D + sub * 8);
            #pragma unroll
            for (int q = 0; q < 8; ++q) acc0[q] += d0 * b2f(v0[q]);
        }
    }

    const float4* bch = (const float4*)(bias + sub * 8);
    float4 bb0 = bch[0], bb1 = bch[1];
    float4 o0, o1;
    o0.x = dd * (acc0[0] + acc1[0]) + bb0.x; o0.y = dd * (acc0[1] + acc1[1]) + bb0.y;
    o0.z = dd * (acc0[2] + acc1[2]) + bb0.z; o0.w = dd * (acc0[3] + acc1[3]) + bb0.w;
    o1.x = dd * (acc0[4] + acc1[4]) + bb1.x; o1.y = dd * (acc0[5] + acc1[5]) + bb1.y;
    o1.z = dd * (acc0[6] + acc1[6]) + bb1.z; o1.w = dd * (acc0[7] + acc1[7]) + bb1.w;
    float4* op = (float4*)(out + (size_t)n * D + sub * 8);
    op[0] = o0; op[1] = o1;
}

extern "C" void kernel_launch(void* const* d_in, const int* in_sizes, int n_in,
                              void* d_out, int out_size, void* d_ws, size_t ws_size,
                              hipStream_t stream) {
    const float* x    = (const float*)d_in[0];
    const int*   ei   = (const int*)d_in[1];   // [2, E]: row0=src, row1=dst
    const float* w    = (const float*)d_in[2];
    const float* bias = (const float*)d_in[3];
    float* out = (float*)d_out;

    const int* src = ei;
    const int* dst = ei + N_EDGES;

    // workspace carve
    char* p = (char*)d_ws;
    short* y  = (short*)p;             p += (size_t)N_NODES * D * 2;    // 12.8 MB
    int* deg  = (int*)p;               p += (size_t)N_NODES * 4;        // 200 KB
    unsigned short* colp = (unsigned short*)p;
    p += (size_t)N_NODES * CAP * 2;                                     // 6.4 MB

    k_zero<<<(N_NODES + 255) / 256, 256, 0, stream>>>(deg);
    k_prep<<<PREP_BLOCKS, 256, 0, stream>>>(src, dst, deg, colp, x, w, y);
    k_gather<<<((N_NODES * 16) + 255) / 256, 256, 0, stream>>>(y, deg, colp, bias, out);
}

// Round 14
// 73.560 us; speedup vs baseline: 2.4803x; 1.2147x over previous
//
#include <hip/hip_runtime.h>
#include <hip/hip_bf16.h>

#define N_NODES 50000
#define N_EDGES 625000
#define D 128
#define CAP 64                         // max in-degree slots (mean 12.5; P(>=64) ~ 1e-30)
#define NTILES ((N_NODES + 15) / 16)   // 3125
#define NRANGE 8
#define RSPAN (N_NODES / NRANGE)       // 6250
#define FILL_BLOCKS 1024               // role-A blocks (128 per dst-range group)
#define XW_BLOCKS 1024                 // role-B blocks
#define PSTRIDE ((FILL_BLOCKS / NRANGE) * 256)  // 32768 threads per range-group
#define NE4 (N_EDGES / 4)              // 156250 int4 packets

typedef __attribute__((ext_vector_type(8))) short bf16x8;
typedef __attribute__((ext_vector_type(4))) float f32x4;

__device__ __forceinline__ float b2f(short s) {
    unsigned u = ((unsigned)(unsigned short)s) << 16;
    return __uint_as_float(u);
}
__device__ __forceinline__ short f2b(float f) {
    union { __hip_bfloat16 h; short s; } cv;
    cv.h = __float2bfloat16(f);
    return cv.s;
}

// ---- zero deg (ws poisoned 0xAA once; deg must be zeroed every call) ----
__global__ void k_zero(int* __restrict__ deg) {
    int i = blockIdx.x * 256 + threadIdx.x;
    if (i < N_NODES) deg[i] = 0;
}

// ---- merged prep: blocks [0,1024) build padded CSR (ushort cols), dst
//      range-partitioned (b&7) and loaded as int4 (4 edges / 16B load);
//      blocks [1024,2048) compute y = bf16(x @ W^T) unscaled. ----
__global__ __launch_bounds__(256) void k_prep(const int* __restrict__ src,
                                              const int* __restrict__ dst,
                                              int* __restrict__ deg,
                                              unsigned short* __restrict__ colp,
                                              const float* __restrict__ x,
                                              const float* __restrict__ w,
                                              short* __restrict__ y) {
    int b = blockIdx.x;
    if (b < FILL_BLOCKS) {
        // ---- fill role: range g = b&7; dst read as int4, src scalar-on-hit ----
        int g = b & 7;
        int bg = b >> 3;
        int lo = g * RSPAN, hi = lo + RSPAN;
        for (int e4 = bg * 256 + threadIdx.x; e4 < NE4; e4 += PSTRIDE) {
            int4 d4 = ((const int4*)dst)[e4];
            int e = e4 * 4;
            if (d4.x >= lo && d4.x < hi) {
                int p = atomicAdd(&deg[d4.x], 1);
                if (p < CAP) colp[d4.x * CAP + p] = (unsigned short)src[e + 0];
            }
            if (d4.y >= lo && d4.y < hi) {
                int p = atomicAdd(&deg[d4.y], 1);
                if (p < CAP) colp[d4.y * CAP + p] = (unsigned short)src[e + 1];
            }
            if (d4.z >= lo && d4.z < hi) {
                int p = atomicAdd(&deg[d4.z], 1);
                if (p < CAP) colp[d4.z * CAP + p] = (unsigned short)src[e + 2];
            }
            if (d4.w >= lo && d4.w < hi) {
                int p = atomicAdd(&deg[d4.w], 1);
                if (p < CAP) colp[d4.w * CAP + p] = (unsigned short)src[e + 3];
            }
        }
    } else {
        // ---- xw role ----
        int t = threadIdx.x;
        int wave = t >> 6, lane = t & 63;
        int c0 = wave * 32;
        int lr = lane & 15;
        int lk = (lane >> 4) * 8;

        // persistent W fragments (f32 -> bf16 once): 4 k-steps x 2 col-tiles
        bf16x8 wf0[4], wf1[4];
        {
            const float* wp0 = w + (size_t)(c0 + lr) * D + lk;
            const float* wp1 = wp0 + 16 * D;
            #pragma unroll
            for (int ks = 0; ks < 4; ++ks) {
                f32x4 wa0 = *(const f32x4*)(wp0 + ks * 32);
                f32x4 wb0 = *(const f32x4*)(wp0 + ks * 32 + 4);
                f32x4 wa1 = *(const f32x4*)(wp1 + ks * 32);
                f32x4 wb1 = *(const f32x4*)(wp1 + ks * 32 + 4);
                #pragma unroll
                for (int q = 0; q < 4; ++q) {
                    wf0[ks][q] = f2b(wa0[q]); wf0[ks][q + 4] = f2b(wb0[q]);
                    wf1[ks][q] = f2b(wa1[q]); wf1[ks][q + 4] = f2b(wb1[q]);
                }
            }
        }

        for (int tile = b - FILL_BLOCKS; tile < NTILES; tile += XW_BLOCKS) {
            int row0 = tile * 16;
            const float* ap = x + (size_t)(row0 + lr) * D + lk;
            f32x4 acc0 = {0.f, 0.f, 0.f, 0.f};
            f32x4 acc1 = {0.f, 0.f, 0.f, 0.f};
            #pragma unroll
            for (int ks = 0; ks < 4; ++ks) {
                f32x4 xa = *(const f32x4*)(ap + ks * 32);
                f32x4 xb = *(const f32x4*)(ap + ks * 32 + 4);
                bf16x8 a;
                #pragma unroll
                for (int q = 0; q < 4; ++q) { a[q] = f2b(xa[q]); a[q + 4] = f2b(xb[q]); }
                acc0 = __builtin_amdgcn_mfma_f32_16x16x32_bf16(a, wf0[ks], acc0, 0, 0, 0);
                acc1 = __builtin_amdgcn_mfma_f32_16x16x32_bf16(a, wf1[ks], acc1, 0, 0, 0);
            }
            // D layout: col = lane&15, row = (lane>>4)*4 + i (m89-verified)
            int orow = row0 + (lane >> 4) * 4;
            int oc0 = c0 + lr, oc1 = c0 + 16 + lr;
            #pragma unroll
            for (int i = 0; i < 4; ++i) {
                y[(size_t)(orow + i) * D + oc0] = f2b(acc0[i]);
                y[(size_t)(orow + i) * D + oc1] = f2b(acc1[i]);
            }
        }
    }
}

// ---- gather: out[n] = dd*( sum_s ds*y[s] + dd*y[n] ) + bias, d* = rsqrt(deg+1).
//      16 lanes/node; per 16 neighbors: one coalesced ushort index batch +
//      one scattered deg load -> rsqrt; (idx, scale) shfl-broadcast. ----
__global__ __launch_bounds__(256) void k_gather(const short* __restrict__ y,
                                                const int* __restrict__ deg,
                                                const unsigned short* __restrict__ colp,
                                                const float* __restrict__ bias,
                                                float* __restrict__ out) {
    int tid = blockIdx.x * 256 + threadIdx.x;
    int n = tid >> 4;            // node id (16 lanes per node)
    int sub = threadIdx.x & 15;  // 8-channel chunk
    int lane = threadIdx.x & 63;
    int gb = lane & 48;          // 16-lane group base within the wave
    if (n >= N_NODES) return;
    int dn_raw = deg[n];
    float dd = rsqrtf((float)(dn_raw + 1));
    int dn = dn_raw < CAP ? dn_raw : CAP;
    bf16x8 self = *(const bf16x8*)(y + (size_t)n * D + sub * 8);
    float acc0[8], acc1[8];
    #pragma unroll
    for (int q = 0; q < 8; ++q) { acc0[q] = dd * b2f(self[q]); acc1[q] = 0.f; }
    const unsigned short* cp = colp + (size_t)n * CAP;

    for (int bj = 0; bj < dn; bj += 16) {
        int rem = dn - bj;
        int m = rem < 16 ? rem : 16;
        int cidx = 0;
        float cds = 0.f;
        if (sub < m) {
            cidx = cp[bj + sub];                   // one coalesced 32B batch
            cds = rsqrtf((float)(deg[cidx] + 1));  // one scattered 4B/lane
        }
        int j = 0;
        for (; j + 4 <= m; j += 4) {
            int s0 = __shfl(cidx, gb + j + 0);
            int s1 = __shfl(cidx, gb + j + 1);
            int s2 = __shfl(cidx, gb + j + 2);
            int s3 = __shfl(cidx, gb + j + 3);
            float d0 = __shfl(cds, gb + j + 0);
            float d1 = __shfl(cds, gb + j + 1);
            float d2 = __shfl(cds, gb + j + 2);
            float d3 = __shfl(cds, gb + j + 3);
            bf16x8 v0 = *(const bf16x8*)(y + (size_t)s0 * D + sub * 8);
            bf16x8 v1 = *(const bf16x8*)(y + (size_t)s1 * D + sub * 8);
            bf16x8 v2 = *(const bf16x8*)(y + (size_t)s2 * D + sub * 8);
            bf16x8 v3 = *(const bf16x8*)(y + (size_t)s3 * D + sub * 8);
            #pragma unroll
            for (int q = 0; q < 8; ++q) {
                acc0[q] += d0 * b2f(v0[q]) + d2 * b2f(v2[q]);
                acc1[q] += d1 * b2f(v1[q]) + d3 * b2f(v3[q]);
            }
        }
        for (; j < m; ++j) {
            int s0 = __shfl(cidx, gb + j);
            float d0 = __shfl(cds, gb + j);
            bf16x8 v0 = *(const bf16x8*)(y + (size_t)s0 * D + sub * 8);
            #pragma unroll
            for (int q = 0; q < 8; ++q) acc0[q] += d0 * b2f(v0[q]);
        }
    }

    const float4* bch = (const float4*)(bias + sub * 8);
    float4 bb0 = bch[0], bb1 = bch[1];
    float4 o0, o1;
    o0.x = dd * (acc0[0] + acc1[0]) + bb0.x; o0.y = dd * (acc0[1] + acc1[1]) + bb0.y;
    o0.z = dd * (acc0[2] + acc1[2]) + bb0.z; o0.w = dd * (acc0[3] + acc1[3]) + bb0.w;
    o1.x = dd * (acc0[4] + acc1[4]) + bb1.x; o1.y = dd * (acc0[5] + acc1[5]) + bb1.y;
    o1.z = dd * (acc0[6] + acc1[6]) + bb1.z; o1.w = dd * (acc0[7] + acc1[7]) + bb1.w;
    float4* op = (float4*)(out + (size_t)n * D + sub * 8);
    op[0] = o0; op[1] = o1;
}

extern "C" void kernel_launch(void* const* d_in, const int* in_sizes, int n_in,
                              void* d_out, int out_size, void* d_ws, size_t ws_size,
                              hipStream_t stream) {
    const float* x    = (const float*)d_in[0];
    const int*   ei   = (const int*)d_in[1];   // [2, E]: row0=src, row1=dst
    const float* w    = (const float*)d_in[2];
    const float* bias = (const float*)d_in[3];
    float* out = (float*)d_out;

    const int* src = ei;
    const int* dst = ei + N_EDGES;

    // workspace carve
    char* p = (char*)d_ws;
    short* y  = (short*)p;             p += (size_t)N_NODES * D * 2;    // 12.8 MB
    int* deg  = (int*)p;               p += (size_t)N_NODES * 4;        // 200 KB
    unsigned short* colp = (unsigned short*)p;
    p += (size_t)N_NODES * CAP * 2;                                     // 6.4 MB

    k_zero<<<(N_NODES + 255) / 256, 256, 0, stream>>>(deg);
    k_prep<<<FILL_BLOCKS + XW_BLOCKS, 256, 0, stream>>>(src, dst, deg, colp, x, w, y);
    k_gather<<<((N_NODES * 16) + 255) / 256, 256, 0, stream>>>(y, deg, colp, bias, out);
}